// Round 1
// baseline (433.728 us; speedup 1.0000x reference)
//
#include <hip/hip_runtime.h>

typedef __attribute__((ext_vector_type(8))) short short8;
typedef __attribute__((ext_vector_type(4))) float f32x4;
typedef __attribute__((ext_vector_type(4))) unsigned int u32x4;

#define NNODES 200
#define NEDGE  8000
#define NF1    8192
#define NH     2048
#define NCL    512
#define K1     24576
#define K2     6144
#define MROWS  448
#define MV     400
#define KC1    16
#define BK1    1536
#define KC2    16
#define BK2    384

#define OFF_P1  0ull
#define SZ_P1   (16ull*MROWS*NH*4)
#define OFF_P2  (OFF_P1 + SZ_P1)
#define SZ_P2   (16ull*MROWS*NCL*4)
#define OFF_A1  (OFF_P2 + SZ_P2)
#define SZ_A1   ((unsigned long long)MROWS*K1*2)
#define OFF_A2  (OFF_A1 + SZ_A1)
#define SZ_A2   ((unsigned long long)MROWS*K2*2)
#define OFF_DEG (OFF_A2 + SZ_A2)
#define OFF_LD  (OFF_DEG + 2048)
#define OFF_LL  (OFF_LD + 320000ull)

static __device__ __forceinline__ unsigned short f2bf(float f) {
  unsigned int u = __float_as_uint(f);
  unsigned int r = (u + 0x7fffu + ((u >> 16) & 1u)) >> 16;
  return (unsigned short)r;
}

__global__ void k_zero(f32x4* p1, int n1, f32x4* p2, int n2, f32x4* p3, int n3) {
  int i = blockIdx.x * 256 + threadIdx.x;
  f32x4 z = {0.f, 0.f, 0.f, 0.f};
  if (i < n1) p1[i] = z;
  i -= n1;
  if (i >= 0 && i < n2) p2[i] = z;
  i -= n2;
  if (i >= 0 && i < n3) p3[i] = z;
}

__global__ void k_deg(const int* __restrict__ ei1, const float* __restrict__ ew1,
                      const int* __restrict__ ei2, const float* __restrict__ ew2,
                      float* __restrict__ deg) {
  int e = blockIdx.x * 256 + threadIdx.x;
  if (e >= 2 * NEDGE) return;
  int g = e / NEDGE, k = e % NEDGE;
  const int* ei = g ? ei2 : ei1;
  const float* ew = g ? ew2 : ew1;
  atomicAdd(deg + g * NNODES + ei[k], ew[k]);
}

__global__ void k_buildL(const int* __restrict__ ei1, const float* __restrict__ ew1,
                         const int* __restrict__ ei2, const float* __restrict__ ew2,
                         const float* __restrict__ deg, float* __restrict__ Ld) {
  int e = blockIdx.x * 256 + threadIdx.x;
  if (e >= 2 * NEDGE) return;
  int g = e / NEDGE, k = e % NEDGE;
  const int* ei = g ? ei2 : ei1;
  const float* ew = g ? ew2 : ew1;
  int r = ei[k], c = ei[NEDGE + k];
  float dr = deg[g * NNODES + r], dc = deg[g * NNODES + c];
  float ir = dr > 0.f ? 1.0f / sqrtf(dr) : 0.f;
  float ic = dc > 0.f ? 1.0f / sqrtf(dc) : 0.f;
  float nrm = -ir * ew[k] * ic;
  atomicAdd(Ld + ((size_t)g * NNODES + c) * NNODES + r, nrm);
}

__global__ void k_LL(const float* __restrict__ Ld, unsigned short* __restrict__ LLb) {
  int b = blockIdx.x;
  int g = b / NNODES, i = b % NNODES;
  __shared__ float Lr[NNODES];
  const float* Lg = Ld + (size_t)g * NNODES * NNODES;
  int t = threadIdx.x;
  if (t < NNODES) Lr[t] = Lg[i * NNODES + t];
  __syncthreads();
  if (t < NNODES) {
    float acc = 0.f;
    for (int k = 0; k < NNODES; ++k) acc = fmaf(Lr[k], Lg[k * NNODES + t], acc);
    unsigned short* LLg = LLb + (size_t)g * MROWS * 224;
    LLg[(size_t)i * 224 + t] = f2bf(Lr[t]);
    LLg[(size_t)(NNODES + i) * 224 + t] = f2bf(2.f * acc - (i == t ? 1.f : 0.f));
  }
}

__global__ void k_t0(const float* __restrict__ x1, const float* __restrict__ x2,
                     unsigned short* __restrict__ A1) {
  int gid = blockIdx.x * 256 + threadIdx.x;
  int row = gid / (NF1 / 8);
  int c8 = (gid % (NF1 / 8)) * 8;
  const float* xp = (row < NNODES ? x1 + (size_t)row * NF1
                                  : x2 + (size_t)(row - NNODES) * NF1) + c8;
  f32x4 a = *(const f32x4*)xp;
  f32x4 b = *(const f32x4*)(xp + 4);
  u32x4 o;
  o[0] = (unsigned)f2bf(a[0]) | ((unsigned)f2bf(a[1]) << 16);
  o[1] = (unsigned)f2bf(a[2]) | ((unsigned)f2bf(a[3]) << 16);
  o[2] = (unsigned)f2bf(b[0]) | ((unsigned)f2bf(b[1]) << 16);
  o[3] = (unsigned)f2bf(b[2]) | ((unsigned)f2bf(b[3]) << 16);
  *(u32x4*)(A1 + (size_t)row * K1 + c8) = o;
}

__global__ __launch_bounds__(256, 1)
void k_abuild(const unsigned short* __restrict__ LLb, const unsigned short* __restrict__ Asrc,
              unsigned short* __restrict__ Adst, const int Nf, const int Ka) {
  __shared__ __align__(16) unsigned short XF[7][4][64][8];
  const int g = blockIdx.x & 1;
  const int nt = blockIdx.x >> 1;
  const int nbase = nt * 64;
  const int t = threadIdx.x;

  #pragma unroll
  for (int it = 0; it < 14; ++it) {
    const int pos = it * 256 + t;
    const int j = pos >> 4;
    const int n4 = (pos & 15) * 4;
    unsigned long long v = 0ull;
    if (j < NNODES)
      v = *(const unsigned long long*)(Asrc + (size_t)(g * NNODES + j) * Ka + nbase + n4);
    const int ks = j >> 5, kg = (j >> 3) & 3, jj = j & 7;
    #pragma unroll
    for (int e = 0; e < 4; ++e) {
      const int nn = n4 + e;
      XF[ks][nn >> 4][(nn & 15) + 16 * kg][jj] = (unsigned short)(v >> (16 * e));
    }
  }
  __syncthreads();

  const int w = t >> 6, lane = t & 63;
  const int lm = lane & 15, lk8 = (lane >> 4) * 8;
  f32x4 acc[7][4];
  #pragma unroll
  for (int i = 0; i < 7; ++i)
    #pragma unroll
    for (int j = 0; j < 4; ++j) acc[i][j] = (f32x4){0.f, 0.f, 0.f, 0.f};

  const unsigned short* LLg = LLb + (size_t)g * MROWS * 224;
  #pragma unroll
  for (int ks = 0; ks < 7; ++ks) {
    short8 bfr[4];
    #pragma unroll
    for (int nf = 0; nf < 4; ++nf) bfr[nf] = *(const short8*)&XF[ks][nf][lane][0];
    short8 af[7];
    #pragma unroll
    for (int mf = 0; mf < 7; ++mf)
      af[mf] = *(const short8*)(LLg + (size_t)(w * 112 + mf * 16 + lm) * 224 + ks * 32 + lk8);
    #pragma unroll
    for (int mf = 0; mf < 7; ++mf)
      #pragma unroll
      for (int nf = 0; nf < 4; ++nf)
        acc[mf][nf] = __builtin_amdgcn_mfma_f32_16x16x32_bf16(af[mf], bfr[nf], acc[mf][nf], 0, 0, 0);
  }

  const int lr4 = (lane >> 4) * 4;
  #pragma unroll
  for (int mf = 0; mf < 7; ++mf) {
    #pragma unroll
    for (int ri = 0; ri < 4; ++ri) {
      const int m = w * 112 + mf * 16 + lr4 + ri;
      if (m < MV) {
        const int drow = g * NNODES + (m < NNODES ? m : m - NNODES);
        const size_t dbase = (size_t)drow * Ka + (m < NNODES ? Nf : 2 * Nf) + nbase + lm;
        #pragma unroll
        for (int nf = 0; nf < 4; ++nf)
          Adst[dbase + nf * 16] = f2bf(acc[mf][nf][ri]);
      }
    }
  }
}

template <int BN, int WN>
__global__ __launch_bounds__(256 * WN, 1)
void k_gemm(const float* __restrict__ W, const unsigned short* __restrict__ A,
            float* __restrict__ P, const int Nn, const int Kc, const int BK, const int Ka) {
  constexpr int NT = 256 * WN;
  constexpr int NFQ = BN / 16;
  constexpr int NFW = NFQ / WN;
  constexpr int RPP = (NT * 4) / BN;
  __shared__ __align__(16) unsigned short WF[2][2][NFQ][64][8];

  const int t = threadIdx.x;
  const int w = t >> 6, lane = t & 63;
  const int wm = w / WN, wn = w % WN;
  const int lm = lane & 15, lk8 = (lane >> 4) * 8;
  const int kc = blockIdx.x % Kc;
  const int nt = blockIdx.x / Kc;
  const int kbase = kc * BK;
  const int nbase = nt * BN;

  const int skk = t / (BN / 4);
  const int sn4 = (t % (BN / 4)) * 4;

  f32x4 wreg[2];
  auto loadW = [&](int kt) {
    const float* p = W + (size_t)(kbase + kt * 64 + skk) * Nn + (nbase + sn4);
    wreg[0] = *(const f32x4*)p;
    wreg[1] = *(const f32x4*)(p + (size_t)RPP * Nn);
  };
  auto storeW = [&](int buf) {
    #pragma unroll
    for (int pp = 0; pp < 2; ++pp) {
      const int kk = skk + pp * RPP;
      const int ks = kk >> 5, kg = (kk >> 3) & 3, jj = kk & 7;
      #pragma unroll
      for (int e = 0; e < 4; ++e) {
        const int nn = sn4 + e;
        WF[buf][ks][nn >> 4][(nn & 15) + 16 * kg][jj] = f2bf(wreg[pp][e]);
      }
    }
  };

  f32x4 acc[7][NFW];
  #pragma unroll
  for (int i = 0; i < 7; ++i)
    #pragma unroll
    for (int j = 0; j < NFW; ++j) acc[i][j] = (f32x4){0.f, 0.f, 0.f, 0.f};

  const int nks = BK / 64;
  loadW(0);
  storeW(0);
  for (int kt = 0; kt < nks; ++kt) {
    if (kt + 1 < nks) loadW(kt + 1);
    __syncthreads();
    const int cur = kt & 1;
    #pragma unroll
    for (int ks = 0; ks < 2; ++ks) {
      short8 bfr[NFW];
      #pragma unroll
      for (int nf = 0; nf < NFW; ++nf)
        bfr[nf] = *(const short8*)&WF[cur][ks][wn * NFW + nf][lane][0];
      short8 af[7];
      #pragma unroll
      for (int mf = 0; mf < 7; ++mf) {
        const int row = wm * 112 + mf * 16 + lm;
        af[mf] = *(const short8*)(A + (size_t)row * Ka + (kbase + kt * 64 + ks * 32 + lk8));
      }
      #pragma unroll
      for (int mf = 0; mf < 7; ++mf)
        #pragma unroll
        for (int nf = 0; nf < NFW; ++nf)
          acc[mf][nf] = __builtin_amdgcn_mfma_f32_16x16x32_bf16(af[mf], bfr[nf], acc[mf][nf], 0, 0, 0);
    }
    __syncthreads();
    if (kt + 1 < nks) storeW((kt + 1) & 1);
  }

  float* Pk = P + (size_t)kc * MROWS * Nn;
  #pragma unroll
  for (int mf = 0; mf < 7; ++mf) {
    const int row = wm * 112 + mf * 16 + ((lane >> 4) << 2);
    #pragma unroll
    for (int nf = 0; nf < NFW; ++nf) {
      const int col = nbase + (wn * NFW + nf) * 16 + lm;
      #pragma unroll
      for (int ri = 0; ri < 4; ++ri)
        Pk[(size_t)(row + ri) * Nn + col] = acc[mf][nf][ri];
    }
  }
}

__global__ void k_ep1(const float* __restrict__ P1, const float* __restrict__ b1,
                      unsigned short* __restrict__ A2) {
  int gid = blockIdx.x * 256 + threadIdx.x;
  int row = gid / (NH / 4);
  int c = (gid % (NH / 4)) * 4;
  f32x4 s = {0.f, 0.f, 0.f, 0.f};
  #pragma unroll
  for (int kc = 0; kc < KC1; ++kc)
    s += *(const f32x4*)(P1 + ((size_t)kc * MROWS + row) * NH + c);
  const f32x4 b = *(const f32x4*)(b1 + c);
  unsigned long long pack = 0;
  #pragma unroll
  for (int i = 0; i < 4; ++i) {
    float v = s[i] + b[i];
    pack |= (unsigned long long)f2bf(v > 0.f ? v : 0.f) << (16 * i);
  }
  *(unsigned long long*)(A2 + (size_t)row * K2 + c) = pack;
}

__global__ __launch_bounds__(256)
void k_cls(const float* __restrict__ P2, const float* __restrict__ b2,
           const float* __restrict__ Wc1, const float* __restrict__ bc1,
           const float* __restrict__ Wc2, const float* __restrict__ bc2,
           const float* __restrict__ Wc3, const float* __restrict__ bc3,
           float* __restrict__ outp) {
  const int g = blockIdx.x >> 5;
  const int rt = blockIdx.x & 31;
  const int r0 = rt * 16;
  __shared__ float zs[16 * 209];
  __shared__ float h1s[16 * 105];
  __shared__ float h2s[16 * 51];
  const int t = threadIdx.x;
  const int r = t & 15;
  const int q = t >> 4;

  const float bb = b2[r0 + r];
  for (int jj = 0; jj < 13; ++jj) {
    int j = jj * 16 + q;
    if (j < NNODES) {
      float s = bb;
      size_t base = (size_t)(g * NNODES + j) * NCL + r0 + r;
      #pragma unroll
      for (int kc = 0; kc < KC2; ++kc) s += P2[(size_t)kc * MROWS * NCL + base];
      zs[r * 209 + j] = s;
    }
  }
  __syncthreads();

  float a1[7];
  #pragma unroll
  for (int ci = 0; ci < 7; ++ci) {
    int c = q * 7 + ci;
    a1[ci] = (c < 100) ? bc1[c] : 0.f;
  }
  for (int j = 0; j < NNODES; ++j) {
    float zv = zs[r * 209 + j];
    #pragma unroll
    for (int ci = 0; ci < 7; ++ci) {
      int c = q * 7 + ci;
      if (c < 100) a1[ci] = fmaf(zv, Wc1[c * 200 + j], a1[ci]);
    }
  }
  #pragma unroll
  for (int ci = 0; ci < 7; ++ci) {
    int c = q * 7 + ci;
    if (c < 100) h1s[r * 105 + c] = a1[ci] > 0.f ? a1[ci] : 0.f;
  }
  __syncthreads();

  float a2[4];
  #pragma unroll
  for (int ci = 0; ci < 4; ++ci) {
    int c2 = q * 4 + ci;
    a2[ci] = (c2 < 50) ? bc2[c2] : 0.f;
  }
  for (int c = 0; c < 100; ++c) {
    float hv = h1s[r * 105 + c];
    #pragma unroll
    for (int ci = 0; ci < 4; ++ci) {
      int c2 = q * 4 + ci;
      if (c2 < 50) a2[ci] = fmaf(hv, Wc2[c2 * 100 + c], a2[ci]);
    }
  }
  #pragma unroll
  for (int ci = 0; ci < 4; ++ci) {
    int c2 = q * 4 + ci;
    if (c2 < 50) h2s[r * 51 + c2] = a2[ci] > 0.f ? a2[ci] : 0.f;
  }
  __syncthreads();

  if (t < 16) {
    float acc = bc3[0];
    for (int c2 = 0; c2 < 50; ++c2) acc = fmaf(h2s[t * 51 + c2], Wc3[c2], acc);
    outp[g * NCL + r0 + t] = acc;
  }
}

extern "C" void kernel_launch(void* const* d_in, const int* in_sizes, int n_in,
                              void* d_out, int out_size, void* d_ws, size_t ws_size,
                              hipStream_t stream) {
  const float* x1  = (const float*)d_in[0];
  const int*   ei1 = (const int*)d_in[1];
  const float* ea1 = (const float*)d_in[2];
  const float* x2  = (const float*)d_in[3];
  const int*   ei2 = (const int*)d_in[4];
  const float* ea2 = (const float*)d_in[5];
  const float* W1  = (const float*)d_in[6];
  const float* b1  = (const float*)d_in[7];
  const float* W2  = (const float*)d_in[8];
  const float* b2  = (const float*)d_in[9];
  const float* Wc1 = (const float*)d_in[10];
  const float* bc1 = (const float*)d_in[11];
  const float* Wc2 = (const float*)d_in[12];
  const float* bc2 = (const float*)d_in[13];
  const float* Wc3 = (const float*)d_in[14];
  const float* bc3 = (const float*)d_in[15];
  float* outp = (float*)d_out;

  char* ws = (char*)d_ws;
  float*          P1  = (float*)(ws + OFF_P1);
  float*          P2  = (float*)(ws + OFF_P2);
  unsigned short* A1  = (unsigned short*)(ws + OFF_A1);
  unsigned short* A2  = (unsigned short*)(ws + OFF_A2);
  float*          deg = (float*)(ws + OFF_DEG);
  float*          Ld  = (float*)(ws + OFF_LD);
  unsigned short* LLb = (unsigned short*)(ws + OFF_LL);

  k_zero<<<897, 256, 0, stream>>>(
      (f32x4*)(ws + OFF_DEG), 45216,
      (f32x4*)(ws + OFF_A1 + (size_t)MV * K1 * 2), 147456,
      (f32x4*)(ws + OFF_A2 + (size_t)MV * K2 * 2), 36864);

  k_deg<<<63, 256, 0, stream>>>(ei1, ea1, ei2, ea2, deg);
  k_buildL<<<63, 256, 0, stream>>>(ei1, ea1, ei2, ea2, deg, Ld);
  k_LL<<<400, 256, 0, stream>>>(Ld, LLb);
  k_t0<<<1600, 256, 0, stream>>>(x1, x2, A1);
  k_abuild<<<(NF1 / 64) * 2, 256, 0, stream>>>(LLb, A1, A1, NF1, K1);
  k_gemm<64, 2><<<KC1 * (NH / 64), 512, 0, stream>>>(W1, A1, P1, NH, KC1, BK1, K1);
  k_ep1<<<800, 256, 0, stream>>>(P1, b1, A2);
  k_abuild<<<(NH / 64) * 2, 256, 0, stream>>>(LLb, A2, A2, NH, K2);
  k_gemm<32, 1><<<KC2 * (NCL / 32), 256, 0, stream>>>(W2, A2, P2, NCL, KC2, BK2, K2);
  k_cls<<<64, 256, 0, stream>>>(P2, b2, Wc1, bc1, Wc2, bc2, Wc3, bc3, outp);
}

// Round 3
// 328.608 us; speedup vs baseline: 1.3199x; 1.3199x over previous
//
#include <hip/hip_runtime.h>

typedef __attribute__((ext_vector_type(8))) short short8;
typedef __attribute__((ext_vector_type(4))) float f32x4;
typedef __attribute__((ext_vector_type(2))) float f32x2;
typedef __attribute__((ext_vector_type(4))) unsigned int u32x4;

#define NNODES 200
#define NEDGE  8000
#define NF1    8192
#define NH     2048
#define NCL    512
#define K1     24576
#define K2     6144
#define MR     512      // padded rows (2 graphs * 200 -> 400 valid)
#define MV     400
#define PV     400      // P partial row stride (valid rows only)
#define KC1    16
#define BK1    1536
#define KC2    16
#define BK2    384

// ---------------- workspace layout (bytes) ----------------
#define OFF_P1  0ull
#define SZ_P1   (16ull*PV*NH*4)            // 52,428,800
#define OFF_P2  (OFF_P1 + SZ_P1)
#define SZ_P2   (16ull*PV*NCL*4)           // 13,107,200
#define OFF_A1  (OFF_P2 + SZ_P2)           // 65,536,000
#define SZ_A1   ((unsigned long long)MR*K1*2)  // 25,165,824
#define OFF_A2  (OFF_A1 + SZ_A1)           // 90,701,824
#define SZ_A2   ((unsigned long long)MR*K2*2)  // 6,291,456
#define OFF_DEG (OFF_A2 + SZ_A2)           // 96,993,280
#define OFF_LD  (OFF_DEG + 2048)
#define OFF_LL  (OFF_LD + 320000ull)       // LL: 2*512*224*2 = 458,752  (end ~97.8MB)

static __device__ __forceinline__ unsigned short f2bf(float f) {
  unsigned int u = __float_as_uint(f);
  unsigned int r = (u + 0x7fffu + ((u >> 16) & 1u)) >> 16;
  return (unsigned short)r;
}
static __device__ __forceinline__ unsigned packbf(float a, float b) {
  return (unsigned)f2bf(a) | ((unsigned)f2bf(b) << 16);
}

// ---------------- zero scratch regions ----------------
__global__ void k_zero(f32x4* p1, int n1, f32x4* p2, int n2, f32x4* p3, int n3) {
  int i = blockIdx.x * 256 + threadIdx.x;
  f32x4 z = {0.f, 0.f, 0.f, 0.f};
  if (i < n1) p1[i] = z;
  i -= n1;
  if (i >= 0 && i < n2) p2[i] = z;
  i -= n2;
  if (i >= 0 && i < n3) p3[i] = z;
}

__global__ void k_deg(const int* __restrict__ ei1, const float* __restrict__ ew1,
                      const int* __restrict__ ei2, const float* __restrict__ ew2,
                      float* __restrict__ deg) {
  int e = blockIdx.x * 256 + threadIdx.x;
  if (e >= 2 * NEDGE) return;
  int g = e / NEDGE, k = e % NEDGE;
  const int* ei = g ? ei2 : ei1;
  const float* ew = g ? ew2 : ew1;
  atomicAdd(deg + g * NNODES + ei[k], ew[k]);
}

__global__ void k_buildL(const int* __restrict__ ei1, const float* __restrict__ ew1,
                         const int* __restrict__ ei2, const float* __restrict__ ew2,
                         const float* __restrict__ deg, float* __restrict__ Ld) {
  int e = blockIdx.x * 256 + threadIdx.x;
  if (e >= 2 * NEDGE) return;
  int g = e / NEDGE, k = e % NEDGE;
  const int* ei = g ? ei2 : ei1;
  const float* ew = g ? ew2 : ew1;
  int r = ei[k], c = ei[NEDGE + k];
  float dr = deg[g * NNODES + r], dc = deg[g * NNODES + c];
  float ir = dr > 0.f ? 1.0f / sqrtf(dr) : 0.f;
  float ic = dc > 0.f ? 1.0f / sqrtf(dc) : 0.f;
  float nrm = -ir * ew[k] * ic;
  atomicAdd(Ld + ((size_t)g * NNODES + c) * NNODES + r, nrm);
}

// LL rows [0,200): L ; rows [200,400): 2L^2-I   (bf16, stride 224, 512-row panels)
__global__ void k_LL(const float* __restrict__ Ld, unsigned short* __restrict__ LLb) {
  int b = blockIdx.x;
  int g = b / NNODES, i = b % NNODES;
  __shared__ float Lr[NNODES];
  const float* Lg = Ld + (size_t)g * NNODES * NNODES;
  int t = threadIdx.x;
  if (t < NNODES) Lr[t] = Lg[i * NNODES + t];
  __syncthreads();
  if (t < NNODES) {
    float acc = 0.f;
    for (int k = 0; k < NNODES; ++k) acc = fmaf(Lr[k], Lg[k * NNODES + t], acc);
    unsigned short* LLg = LLb + (size_t)g * MR * 224;
    LLg[(size_t)i * 224 + t] = f2bf(Lr[t]);
    LLg[(size_t)(NNODES + i) * 224 + t] = f2bf(2.f * acc - (i == t ? 1.f : 0.f));
  }
}

__global__ void k_t0(const float* __restrict__ x1, const float* __restrict__ x2,
                     unsigned short* __restrict__ A1) {
  int gid = blockIdx.x * 256 + threadIdx.x;
  int row = gid / (NF1 / 8);
  int c8 = (gid % (NF1 / 8)) * 8;
  const float* xp = (row < NNODES ? x1 + (size_t)row * NF1
                                  : x2 + (size_t)(row - NNODES) * NF1) + c8;
  f32x4 a = *(const f32x4*)xp;
  f32x4 b = *(const f32x4*)(xp + 4);
  u32x4 o;
  o[0] = packbf(a[0], a[1]);
  o[1] = packbf(a[2], a[3]);
  o[2] = packbf(b[0], b[1]);
  o[3] = packbf(b[2], b[3]);
  *(u32x4*)(A1 + (size_t)row * K1 + c8) = o;
}

// builds T1/T2 column blocks:  [T1;T2](:, nt*64..) = LL @ T0(:, nt*64..)
__global__ __launch_bounds__(256, 1)
void k_abuild(const unsigned short* __restrict__ LLb, const unsigned short* __restrict__ Asrc,
              unsigned short* __restrict__ Adst, const int Nf, const int Ka) {
  __shared__ __align__(16) unsigned short XF[7][4][64][8];
  const int g = blockIdx.x & 1;
  const int nt = blockIdx.x >> 1;
  const int nbase = nt * 64;
  const int t = threadIdx.x;

  #pragma unroll
  for (int it = 0; it < 14; ++it) {
    const int pos = it * 256 + t;
    const int j = pos >> 4;
    const int n4 = (pos & 15) * 4;
    unsigned long long v = 0ull;
    if (j < NNODES)
      v = *(const unsigned long long*)(Asrc + (size_t)(g * NNODES + j) * Ka + nbase + n4);
    const int ks = j >> 5, kg = (j >> 3) & 3, jj = j & 7;
    #pragma unroll
    for (int e = 0; e < 4; ++e) {
      const int nn = n4 + e;
      XF[ks][nn >> 4][(nn & 15) + 16 * kg][jj] = (unsigned short)(v >> (16 * e));
    }
  }
  __syncthreads();

  const int w = t >> 6, lane = t & 63;
  const int lm = lane & 15, lk8 = (lane >> 4) * 8;
  f32x4 acc[7][4];
  #pragma unroll
  for (int i = 0; i < 7; ++i)
    #pragma unroll
    for (int j = 0; j < 4; ++j) acc[i][j] = (f32x4){0.f, 0.f, 0.f, 0.f};

  const unsigned short* LLg = LLb + (size_t)g * MR * 224;
  #pragma unroll
  for (int ks = 0; ks < 7; ++ks) {
    short8 bfr[4];
    #pragma unroll
    for (int nf = 0; nf < 4; ++nf) bfr[nf] = *(const short8*)&XF[ks][nf][lane][0];
    short8 af[7];
    #pragma unroll
    for (int mf = 0; mf < 7; ++mf)
      af[mf] = *(const short8*)(LLg + (size_t)(w * 112 + mf * 16 + lm) * 224 + ks * 32 + lk8);
    #pragma unroll
    for (int mf = 0; mf < 7; ++mf)
      #pragma unroll
      for (int nf = 0; nf < 4; ++nf)
        acc[mf][nf] = __builtin_amdgcn_mfma_f32_16x16x32_bf16(af[mf], bfr[nf], acc[mf][nf], 0, 0, 0);
  }

  const int lr4 = (lane >> 4) * 4;
  #pragma unroll
  for (int mf = 0; mf < 7; ++mf) {
    #pragma unroll
    for (int ri = 0; ri < 4; ++ri) {
      const int m = w * 112 + mf * 16 + lr4 + ri;
      if (m < MV) {
        const int drow = g * NNODES + (m < NNODES ? m : m - NNODES);
        const size_t dbase = (size_t)drow * Ka + (m < NNODES ? Nf : 2 * Nf) + nbase + lm;
        #pragma unroll
        for (int nf = 0; nf < 4; ++nf)
          Adst[dbase + nf * 16] = f2bf(acc[mf][nf][ri]);
      }
    }
  }
}

// ---------------- main split-K GEMM ----------------
// P[kc][row<400][Nn] = A[512 x BK-slice] @ bf16(W[BK-slice x BN-tile])
// A-tile (512x64 bf16) in LDS, XOR-swizzled rows; W tile in MFMA frag layout.
template <int BN>
__global__ __launch_bounds__(512, 2)
void k_gemm(const float* __restrict__ W, const unsigned short* __restrict__ A,
            float* __restrict__ P, const int Nn, const int BK, const int Ka) {
  constexpr int NF = BN / 16;     // 16-col frags in tile
  constexpr int NFW = BN / 32;    // frags per wave (2-way wn split)
  __shared__ __align__(16) unsigned short Atile[MR * 64];          // 64 KB
  __shared__ __align__(16) unsigned short Wt[2 * NF * 64 * 8];     // ks-dim x frag layout

  const int t = threadIdx.x;
  const int w = t >> 6, lane = t & 63;
  const int wm = w >> 1, wn = w & 1;
  const int lm = lane & 15;
  const int l4 = lane >> 4;
  const int kc = blockIdx.x & 15;
  const int nt = blockIdx.x >> 4;
  const int kbase = kc * BK;
  const int nbase = nt * BN;
  const int nks = BK >> 6;

  // ---- A staging geometry (8 x 16B per thread, fixed) ----
  int offAg[8];   // global byte offset (from A base + kbase)
  int offAl[8];   // lds byte offset
  #pragma unroll
  for (int c = 0; c < 8; ++c) {
    const int off = c * 8192 + t * 16;
    const int row = off >> 7;
    const int rb = off & 127;
    const int gb = rb ^ ((row & 7) << 4);
    offAg[c] = row * (Ka * 2) + gb;
    offAl[c] = off;
  }
  const char* Ab = (const char*)A + (size_t)kbase * 2;

  // ---- W staging geometry ----
  constexpr int RW = (BN == 128) ? 4 : 2;   // rows per thread
  constexpr int CW = (BN == 128) ? 4 : 2;   // cols per thread
  const int kk0 = (BN == 128) ? ((t >> 5) * 4) : ((t >> 4) * 2);
  const int colb = (BN == 128) ? ((t & 31) * 4) : ((t & 15) * 2);
  int offWg[RW];                            // global float offsets (from W base)
  #pragma unroll
  for (int r = 0; r < RW; ++r)
    offWg[r] = (kbase + kk0 + r) * Nn + nbase + colb;
  int offWl[RW / 2][CW];                    // lds u32 indices
  #pragma unroll
  for (int pr = 0; pr < RW / 2; ++pr) {
    const int kk = kk0 + 2 * pr;
    const int ks = kk >> 5, kg = (kk >> 3) & 3, jj1 = (kk & 7) >> 1;
    #pragma unroll
    for (int e = 0; e < CW; ++e) {
      const int nn = colb + e;
      const int nf = nn >> 4;
      const int ln = ((nn & 15) + 16 * kg) ^ (nf & 3);
      offWl[pr][e] = ((ks * NF + nf) * 64 + ln) * 4 + jj1;
    }
  }

  // ---- fragment read addresses (bytes, fixed) ----
  int aAddr[8];
  #pragma unroll
  for (int mf = 0; mf < 8; ++mf) {
    const int row = wm * 128 + mf * 16 + lm;
    aAddr[mf] = row * 128 + ((l4 * 16) ^ ((row & 7) << 4));
  }
  int bAddr[NFW];
  #pragma unroll
  for (int nf = 0; nf < NFW; ++nf) {
    const int nfg = wn * NFW + nf;
    bAddr[nf] = ((nfg * 64) + (lane ^ (nfg & 3))) * 16;
  }
  constexpr int BSTRIDE = NF * 64 * 16;   // ks=1 byte offset in Wt

  f32x4 acc[8][NFW];
  #pragma unroll
  for (int i = 0; i < 8; ++i)
    #pragma unroll
    for (int j = 0; j < NFW; ++j) acc[i][j] = (f32x4){0.f, 0.f, 0.f, 0.f};

  u32x4 areg[8];
  f32x4 wv4[RW];
  f32x2 wv2[RW];

  // prologue: stage kt=0
  #pragma unroll
  for (int c = 0; c < 8; ++c) areg[c] = *(const u32x4*)(Ab + offAg[c]);
  #pragma unroll
  for (int r = 0; r < RW; ++r) {
    if constexpr (BN == 128) wv4[r] = __builtin_nontemporal_load((const f32x4*)(W + offWg[r]));
    else                     wv2[r] = __builtin_nontemporal_load((const f32x2*)(W + offWg[r]));
  }
  {
    #pragma unroll
    for (int c = 0; c < 8; ++c) *(u32x4*)((char*)Atile + offAl[c]) = areg[c];
    unsigned* w32 = (unsigned*)Wt;
    #pragma unroll
    for (int pr = 0; pr < RW / 2; ++pr)
      #pragma unroll
      for (int e = 0; e < CW; ++e) {
        float lo = (BN == 128) ? wv4[2 * pr][e] : wv2[2 * pr][e];
        float hi = (BN == 128) ? wv4[2 * pr + 1][e] : wv2[2 * pr + 1][e];
        w32[offWl[pr][e]] = packbf(lo, hi);
      }
  }
  __syncthreads();

  for (int kt = 0; kt < nks; ++kt) {
    const bool more = (kt + 1 < nks);
    if (more) {
      const int ko = (kt + 1) * 128;
      #pragma unroll
      for (int c = 0; c < 8; ++c) areg[c] = *(const u32x4*)(Ab + offAg[c] + ko);
      const size_t kwo = (size_t)(kt + 1) * 64 * Nn;
      #pragma unroll
      for (int r = 0; r < RW; ++r) {
        if constexpr (BN == 128) wv4[r] = __builtin_nontemporal_load((const f32x4*)(W + offWg[r] + kwo));
        else                     wv2[r] = __builtin_nontemporal_load((const f32x2*)(W + offWg[r] + kwo));
      }
    }
    // compute current tile
    #pragma unroll
    for (int ks = 0; ks < 2; ++ks) {
      short8 bfr[NFW];
      #pragma unroll
      for (int nf = 0; nf < NFW; ++nf)
        bfr[nf] = *(const short8*)((const char*)Wt + bAddr[nf] + ks * BSTRIDE);
      short8 af[8];
      #pragma unroll
      for (int mf = 0; mf < 8; ++mf)
        af[mf] = *(const short8*)((const char*)Atile + (aAddr[mf] ^ (ks * 64)));
      #pragma unroll
      for (int mf = 0; mf < 8; ++mf)
        #pragma unroll
        for (int nf = 0; nf < NFW; ++nf)
          acc[mf][nf] = __builtin_amdgcn_mfma_f32_16x16x32_bf16(af[mf], bfr[nf], acc[mf][nf], 0, 0, 0);
    }
    __syncthreads();
    if (more) {
      #pragma unroll
      for (int c = 0; c < 8; ++c) *(u32x4*)((char*)Atile + offAl[c]) = areg[c];
      unsigned* w32 = (unsigned*)Wt;
      #pragma unroll
      for (int pr = 0; pr < RW / 2; ++pr)
        #pragma unroll
        for (int e = 0; e < CW; ++e) {
          float lo = (BN == 128) ? wv4[2 * pr][e] : wv2[2 * pr][e];
          float hi = (BN == 128) ? wv4[2 * pr + 1][e] : wv2[2 * pr + 1][e];
          w32[offWl[pr][e]] = packbf(lo, hi);
        }
    }
    __syncthreads();
  }

  // epilogue: P[kc][row][nbase+col]
  float* Pk = P + ((size_t)kc * PV) * Nn + nbase;
  #pragma unroll
  for (int mf = 0; mf < 8; ++mf) {
    const int row0 = wm * 128 + mf * 16 + l4 * 4;
    #pragma unroll
    for (int ri = 0; ri < 4; ++ri) {
      const int row = row0 + ri;
      if (row < MV) {
        #pragma unroll
        for (int nf = 0; nf < NFW; ++nf) {
          const int col = (wn * NFW + nf) * 16 + lm;
          __builtin_nontemporal_store(acc[mf][nf][ri], Pk + (size_t)row * Nn + col);
        }
      }
    }
  }
}

// H = relu(sum_kc P1 + b1) -> bf16 into A2 T0 region
__global__ void k_ep1(const float* __restrict__ P1, const float* __restrict__ b1,
                      unsigned short* __restrict__ A2) {
  int gid = blockIdx.x * 256 + threadIdx.x;   // 400*2048/4
  int row = gid / (NH / 4);
  int c = (gid % (NH / 4)) * 4;
  f32x4 s = {0.f, 0.f, 0.f, 0.f};
  #pragma unroll
  for (int kc = 0; kc < KC1; ++kc)
    s += __builtin_nontemporal_load((const f32x4*)(P1 + ((size_t)kc * PV + row) * NH + c));
  const f32x4 b = *(const f32x4*)(b1 + c);
  unsigned long long pack = 0;
  #pragma unroll
  for (int i = 0; i < 4; ++i) {
    float v = s[i] + b[i];
    pack |= (unsigned long long)f2bf(v > 0.f ? v : 0.f) << (16 * i);
  }
  *(unsigned long long*)(A2 + (size_t)row * K2 + c) = pack;
}

__global__ __launch_bounds__(256)
void k_cls(const float* __restrict__ P2, const float* __restrict__ b2,
           const float* __restrict__ Wc1, const float* __restrict__ bc1,
           const float* __restrict__ Wc2, const float* __restrict__ bc2,
           const float* __restrict__ Wc3, const float* __restrict__ bc3,
           float* __restrict__ outp) {
  const int g = blockIdx.x >> 5;
  const int rt = blockIdx.x & 31;
  const int r0 = rt * 16;
  __shared__ float zs[16 * 209];
  __shared__ float h1s[16 * 105];
  __shared__ float h2s[16 * 51];
  const int t = threadIdx.x;
  const int r = t & 15;
  const int q = t >> 4;

  const float bb = b2[r0 + r];
  for (int jj = 0; jj < 13; ++jj) {
    int j = jj * 16 + q;
    if (j < NNODES) {
      float s = bb;
      size_t base = (size_t)(g * NNODES + j) * NCL + r0 + r;
      #pragma unroll
      for (int kc = 0; kc < KC2; ++kc) s += P2[(size_t)kc * PV * NCL + base];
      zs[r * 209 + j] = s;
    }
  }
  __syncthreads();

  float a1[7];
  #pragma unroll
  for (int ci = 0; ci < 7; ++ci) {
    int c = q * 7 + ci;
    a1[ci] = (c < 100) ? bc1[c] : 0.f;
  }
  for (int j = 0; j < NNODES; ++j) {
    float zv = zs[r * 209 + j];
    #pragma unroll
    for (int ci = 0; ci < 7; ++ci) {
      int c = q * 7 + ci;
      if (c < 100) a1[ci] = fmaf(zv, Wc1[c * 200 + j], a1[ci]);
    }
  }
  #pragma unroll
  for (int ci = 0; ci < 7; ++ci) {
    int c = q * 7 + ci;
    if (c < 100) h1s[r * 105 + c] = a1[ci] > 0.f ? a1[ci] : 0.f;
  }
  __syncthreads();

  float a2[4];
  #pragma unroll
  for (int ci = 0; ci < 4; ++ci) {
    int c2 = q * 4 + ci;
    a2[ci] = (c2 < 50) ? bc2[c2] : 0.f;
  }
  for (int c = 0; c < 100; ++c) {
    float hv = h1s[r * 105 + c];
    #pragma unroll
    for (int ci = 0; ci < 4; ++ci) {
      int c2 = q * 4 + ci;
      if (c2 < 50) a2[ci] = fmaf(hv, Wc2[c2 * 100 + c], a2[ci]);
    }
  }
  #pragma unroll
  for (int ci = 0; ci < 4; ++ci) {
    int c2 = q * 4 + ci;
    if (c2 < 50) h2s[r * 51 + c2] = a2[ci] > 0.f ? a2[ci] : 0.f;
  }
  __syncthreads();

  if (t < 16) {
    float acc = bc3[0];
    for (int c2 = 0; c2 < 50; ++c2) acc = fmaf(h2s[t * 51 + c2], Wc3[c2], acc);
    outp[g * NCL + r0 + t] = acc;
  }
}

extern "C" void kernel_launch(void* const* d_in, const int* in_sizes, int n_in,
                              void* d_out, int out_size, void* d_ws, size_t ws_size,
                              hipStream_t stream) {
  const float* x1  = (const float*)d_in[0];
  const int*   ei1 = (const int*)d_in[1];
  const float* ea1 = (const float*)d_in[2];
  const float* x2  = (const float*)d_in[3];
  const int*   ei2 = (const int*)d_in[4];
  const float* ea2 = (const float*)d_in[5];
  const float* W1  = (const float*)d_in[6];
  const float* b1  = (const float*)d_in[7];
  const float* W2  = (const float*)d_in[8];
  const float* b2  = (const float*)d_in[9];
  const float* Wc1 = (const float*)d_in[10];
  const float* bc1 = (const float*)d_in[11];
  const float* Wc2 = (const float*)d_in[12];
  const float* bc2 = (const float*)d_in[13];
  const float* Wc3 = (const float*)d_in[14];
  const float* bc3 = (const float*)d_in[15];
  float* outp = (float*)d_out;

  char* ws = (char*)d_ws;
  float*          P1  = (float*)(ws + OFF_P1);
  float*          P2  = (float*)(ws + OFF_P2);
  unsigned short* A1  = (unsigned short*)(ws + OFF_A1);
  unsigned short* A2  = (unsigned short*)(ws + OFF_A2);
  float*          deg = (float*)(ws + OFF_DEG);
  float*          Ld  = (float*)(ws + OFF_LD);
  unsigned short* LLb = (unsigned short*)(ws + OFF_LL);

  // zero: [deg|Ld|LL] + A1 pad rows (400..511) + A2 pad rows
  k_zero<<<1871, 256, 0, stream>>>(
      (f32x4*)(ws + OFF_DEG), 48800,
      (f32x4*)(ws + OFF_A1 + (size_t)MV * K1 * 2), 344064,
      (f32x4*)(ws + OFF_A2 + (size_t)MV * K2 * 2), 86016);

  k_deg<<<63, 256, 0, stream>>>(ei1, ea1, ei2, ea2, deg);
  k_buildL<<<63, 256, 0, stream>>>(ei1, ea1, ei2, ea2, deg, Ld);
  k_LL<<<400, 256, 0, stream>>>(Ld, LLb);
  k_t0<<<1600, 256, 0, stream>>>(x1, x2, A1);
  k_abuild<<<(NF1 / 64) * 2, 256, 0, stream>>>(LLb, A1, A1, NF1, K1);
  k_gemm<128><<<KC1 * (NH / 128), 512, 0, stream>>>(W1, A1, P1, NH, BK1, K1);
  k_ep1<<<800, 256, 0, stream>>>(P1, b1, A2);
  k_abuild<<<(NH / 64) * 2, 256, 0, stream>>>(LLb, A2, A2, NH, K2);
  k_gemm<32><<<KC2 * (NCL / 32), 512, 0, stream>>>(W2, A2, P2, NCL, BK2, K2);
  k_cls<<<64, 256, 0, stream>>>(P2, b2, Wc1, bc1, Wc2, bc2, Wc3, bc3, outp);
}

// Round 4
// 193.752 us; speedup vs baseline: 2.2386x; 1.6960x over previous
//
#include <hip/hip_runtime.h>

typedef __attribute__((ext_vector_type(8))) short short8;
typedef __attribute__((ext_vector_type(4))) float f32x4;
typedef __attribute__((ext_vector_type(2))) float f32x2;
typedef __attribute__((ext_vector_type(4))) unsigned int u32x4;

#define NNODES 200
#define NEDGE  8000
#define NF1    8192
#define NH     2048
#define NCL    512
#define K1     24576
#define K2     6144
#define MR     512      // padded rows (2 graphs * 200 -> 400 valid)
#define MV     400
#define PV     400      // P partial row stride (valid rows only)
#define KC1    16
#define BK1    1536
#define KC2    16
#define BK2    384

// ---------------- workspace layout (bytes) ----------------
#define OFF_P1  0ull
#define SZ_P1   (16ull*PV*NH*4)            // 52,428,800
#define OFF_P2  (OFF_P1 + SZ_P1)
#define SZ_P2   (16ull*PV*NCL*4)           // 13,107,200
#define OFF_A1  (OFF_P2 + SZ_P2)           // 65,536,000
#define SZ_A1   ((unsigned long long)MR*K1*2)  // 25,165,824
#define OFF_A2  (OFF_A1 + SZ_A1)           // 90,701,824
#define SZ_A2   ((unsigned long long)MR*K2*2)  // 6,291,456
#define OFF_DEG (OFF_A2 + SZ_A2)           // 96,993,280
#define OFF_LD  (OFF_DEG + 2048)
#define OFF_LL  (OFF_LD + 320000ull)       // LL: 2*512*224*2 = 458,752
// zt (classifier input, 2*512*200*4 = 819,200 B) reuses the P1 region (dead by then)
#define OFF_Z   OFF_P1

static __device__ __forceinline__ unsigned short f2bf(float f) {
  unsigned int u = __float_as_uint(f);
  unsigned int r = (u + 0x7fffu + ((u >> 16) & 1u)) >> 16;
  return (unsigned short)r;
}
static __device__ __forceinline__ unsigned packbf(float a, float b) {
  return (unsigned)f2bf(a) | ((unsigned)f2bf(b) << 16);
}

// ---------------- zero scratch regions ----------------
__global__ void k_zero(f32x4* p1, int n1, f32x4* p2, int n2, f32x4* p3, int n3) {
  int i = blockIdx.x * 256 + threadIdx.x;
  f32x4 z = {0.f, 0.f, 0.f, 0.f};
  if (i < n1) p1[i] = z;
  i -= n1;
  if (i >= 0 && i < n2) p2[i] = z;
  i -= n2;
  if (i >= 0 && i < n3) p3[i] = z;
}

__global__ void k_deg(const int* __restrict__ ei1, const float* __restrict__ ew1,
                      const int* __restrict__ ei2, const float* __restrict__ ew2,
                      float* __restrict__ deg) {
  int e = blockIdx.x * 256 + threadIdx.x;
  if (e >= 2 * NEDGE) return;
  int g = e / NEDGE, k = e % NEDGE;
  const int* ei = g ? ei2 : ei1;
  const float* ew = g ? ew2 : ew1;
  atomicAdd(deg + g * NNODES + ei[k], ew[k]);
}

__global__ void k_buildL(const int* __restrict__ ei1, const float* __restrict__ ew1,
                         const int* __restrict__ ei2, const float* __restrict__ ew2,
                         const float* __restrict__ deg, float* __restrict__ Ld) {
  int e = blockIdx.x * 256 + threadIdx.x;
  if (e >= 2 * NEDGE) return;
  int g = e / NEDGE, k = e % NEDGE;
  const int* ei = g ? ei2 : ei1;
  const float* ew = g ? ew2 : ew1;
  int r = ei[k], c = ei[NEDGE + k];
  float dr = deg[g * NNODES + r], dc = deg[g * NNODES + c];
  float ir = dr > 0.f ? 1.0f / sqrtf(dr) : 0.f;
  float ic = dc > 0.f ? 1.0f / sqrtf(dc) : 0.f;
  float nrm = -ir * ew[k] * ic;
  atomicAdd(Ld + ((size_t)g * NNODES + c) * NNODES + r, nrm);
}

// LL rows [0,200): L ; rows [200,400): 2L^2-I   (bf16, stride 224, 512-row panels)
__global__ void k_LL(const float* __restrict__ Ld, unsigned short* __restrict__ LLb) {
  int b = blockIdx.x;
  int g = b / NNODES, i = b % NNODES;
  __shared__ float Lr[NNODES];
  const float* Lg = Ld + (size_t)g * NNODES * NNODES;
  int t = threadIdx.x;
  if (t < NNODES) Lr[t] = Lg[i * NNODES + t];
  __syncthreads();
  if (t < NNODES) {
    float acc = 0.f;
    for (int k = 0; k < NNODES; ++k) acc = fmaf(Lr[k], Lg[k * NNODES + t], acc);
    unsigned short* LLg = LLb + (size_t)g * MR * 224;
    LLg[(size_t)i * 224 + t] = f2bf(Lr[t]);
    LLg[(size_t)(NNODES + i) * 224 + t] = f2bf(2.f * acc - (i == t ? 1.f : 0.f));
  }
}

__global__ void k_t0(const float* __restrict__ x1, const float* __restrict__ x2,
                     unsigned short* __restrict__ A1) {
  int gid = blockIdx.x * 256 + threadIdx.x;
  int row = gid / (NF1 / 8);
  int c8 = (gid % (NF1 / 8)) * 8;
  const float* xp = (row < NNODES ? x1 + (size_t)row * NF1
                                  : x2 + (size_t)(row - NNODES) * NF1) + c8;
  f32x4 a = *(const f32x4*)xp;
  f32x4 b = *(const f32x4*)(xp + 4);
  u32x4 o;
  o[0] = packbf(a[0], a[1]);
  o[1] = packbf(a[2], a[3]);
  o[2] = packbf(b[0], b[1]);
  o[3] = packbf(b[2], b[3]);
  *(u32x4*)(A1 + (size_t)row * K1 + c8) = o;
}

// builds T1/T2 column blocks:  [T1;T2](:, nt*64..) = LL @ T0(:, nt*64..)
__global__ __launch_bounds__(256, 1)
void k_abuild(const unsigned short* __restrict__ LLb, const unsigned short* __restrict__ Asrc,
              unsigned short* __restrict__ Adst, const int Nf, const int Ka) {
  __shared__ __align__(16) unsigned short XF[7][4][64][8];
  const int g = blockIdx.x & 1;
  const int nt = blockIdx.x >> 1;
  const int nbase = nt * 64;
  const int t = threadIdx.x;

  #pragma unroll
  for (int it = 0; it < 14; ++it) {
    const int pos = it * 256 + t;
    const int j = pos >> 4;
    const int n4 = (pos & 15) * 4;
    unsigned long long v = 0ull;
    if (j < NNODES)
      v = *(const unsigned long long*)(Asrc + (size_t)(g * NNODES + j) * Ka + nbase + n4);
    const int ks = j >> 5, kg = (j >> 3) & 3, jj = j & 7;
    #pragma unroll
    for (int e = 0; e < 4; ++e) {
      const int nn = n4 + e;
      XF[ks][nn >> 4][(nn & 15) + 16 * kg][jj] = (unsigned short)(v >> (16 * e));
    }
  }
  __syncthreads();

  const int w = t >> 6, lane = t & 63;
  const int lm = lane & 15, lk8 = (lane >> 4) * 8;
  f32x4 acc[7][4];
  #pragma unroll
  for (int i = 0; i < 7; ++i)
    #pragma unroll
    for (int j = 0; j < 4; ++j) acc[i][j] = (f32x4){0.f, 0.f, 0.f, 0.f};

  const unsigned short* LLg = LLb + (size_t)g * MR * 224;
  #pragma unroll
  for (int ks = 0; ks < 7; ++ks) {
    short8 bfr[4];
    #pragma unroll
    for (int nf = 0; nf < 4; ++nf) bfr[nf] = *(const short8*)&XF[ks][nf][lane][0];
    short8 af[7];
    #pragma unroll
    for (int mf = 0; mf < 7; ++mf)
      af[mf] = *(const short8*)(LLg + (size_t)(w * 112 + mf * 16 + lm) * 224 + ks * 32 + lk8);
    #pragma unroll
    for (int mf = 0; mf < 7; ++mf)
      #pragma unroll
      for (int nf = 0; nf < 4; ++nf)
        acc[mf][nf] = __builtin_amdgcn_mfma_f32_16x16x32_bf16(af[mf], bfr[nf], acc[mf][nf], 0, 0, 0);
  }

  const int lr4 = (lane >> 4) * 4;
  #pragma unroll
  for (int mf = 0; mf < 7; ++mf) {
    #pragma unroll
    for (int ri = 0; ri < 4; ++ri) {
      const int m = w * 112 + mf * 16 + lr4 + ri;
      if (m < MV) {
        const int drow = g * NNODES + (m < NNODES ? m : m - NNODES);
        const size_t dbase = (size_t)drow * Ka + (m < NNODES ? Nf : 2 * Nf) + nbase + lm;
        #pragma unroll
        for (int nf = 0; nf < 4; ++nf)
          Adst[dbase + nf * 16] = f2bf(acc[mf][nf][ri]);
      }
    }
  }
}

// ---------------- main split-K GEMM ----------------
template <int BN>
__global__ __launch_bounds__(512, 2)
void k_gemm(const float* __restrict__ W, const unsigned short* __restrict__ A,
            float* __restrict__ P, const int Nn, const int BK, const int Ka) {
  constexpr int NF = BN / 16;
  constexpr int NFW = BN / 32;
  __shared__ __align__(16) unsigned short Atile[MR * 64];
  __shared__ __align__(16) unsigned short Wt[2 * NF * 64 * 8];

  const int t = threadIdx.x;
  const int w = t >> 6, lane = t & 63;
  const int wm = w >> 1, wn = w & 1;
  const int lm = lane & 15;
  const int l4 = lane >> 4;
  const int kc = blockIdx.x & 15;
  const int nt = blockIdx.x >> 4;
  const int kbase = kc * BK;
  const int nbase = nt * BN;
  const int nks = BK >> 6;

  int offAg[8];
  int offAl[8];
  #pragma unroll
  for (int c = 0; c < 8; ++c) {
    const int off = c * 8192 + t * 16;
    const int row = off >> 7;
    const int rb = off & 127;
    const int gb = rb ^ ((row & 7) << 4);
    offAg[c] = row * (Ka * 2) + gb;
    offAl[c] = off;
  }
  const char* Ab = (const char*)A + (size_t)kbase * 2;

  constexpr int RW = (BN == 128) ? 4 : 2;
  constexpr int CW = (BN == 128) ? 4 : 2;
  const int kk0 = (BN == 128) ? ((t >> 5) * 4) : ((t >> 4) * 2);
  const int colb = (BN == 128) ? ((t & 31) * 4) : ((t & 15) * 2);
  int offWg[RW];
  #pragma unroll
  for (int r = 0; r < RW; ++r)
    offWg[r] = (kbase + kk0 + r) * Nn + nbase + colb;
  int offWl[RW / 2][CW];
  #pragma unroll
  for (int pr = 0; pr < RW / 2; ++pr) {
    const int kk = kk0 + 2 * pr;
    const int ks = kk >> 5, kg = (kk >> 3) & 3, jj1 = (kk & 7) >> 1;
    #pragma unroll
    for (int e = 0; e < CW; ++e) {
      const int nn = colb + e;
      const int nf = nn >> 4;
      const int ln = ((nn & 15) + 16 * kg) ^ (nf & 3);
      offWl[pr][e] = ((ks * NF + nf) * 64 + ln) * 4 + jj1;
    }
  }

  int aAddr[8];
  #pragma unroll
  for (int mf = 0; mf < 8; ++mf) {
    const int row = wm * 128 + mf * 16 + lm;
    aAddr[mf] = row * 128 + ((l4 * 16) ^ ((row & 7) << 4));
  }
  int bAddr[NFW];
  #pragma unroll
  for (int nf = 0; nf < NFW; ++nf) {
    const int nfg = wn * NFW + nf;
    bAddr[nf] = ((nfg * 64) + (lane ^ (nfg & 3))) * 16;
  }
  constexpr int BSTRIDE = NF * 64 * 16;

  f32x4 acc[8][NFW];
  #pragma unroll
  for (int i = 0; i < 8; ++i)
    #pragma unroll
    for (int j = 0; j < NFW; ++j) acc[i][j] = (f32x4){0.f, 0.f, 0.f, 0.f};

  u32x4 areg[8];
  f32x4 wv4[RW];
  f32x2 wv2[RW];

  #pragma unroll
  for (int c = 0; c < 8; ++c) areg[c] = *(const u32x4*)(Ab + offAg[c]);
  #pragma unroll
  for (int r = 0; r < RW; ++r) {
    if constexpr (BN == 128) wv4[r] = __builtin_nontemporal_load((const f32x4*)(W + offWg[r]));
    else                     wv2[r] = __builtin_nontemporal_load((const f32x2*)(W + offWg[r]));
  }
  {
    #pragma unroll
    for (int c = 0; c < 8; ++c) *(u32x4*)((char*)Atile + offAl[c]) = areg[c];
    unsigned* w32 = (unsigned*)Wt;
    #pragma unroll
    for (int pr = 0; pr < RW / 2; ++pr)
      #pragma unroll
      for (int e = 0; e < CW; ++e) {
        float lo = (BN == 128) ? wv4[2 * pr][e] : wv2[2 * pr][e];
        float hi = (BN == 128) ? wv4[2 * pr + 1][e] : wv2[2 * pr + 1][e];
        w32[offWl[pr][e]] = packbf(lo, hi);
      }
  }
  __syncthreads();

  for (int kt = 0; kt < nks; ++kt) {
    const bool more = (kt + 1 < nks);
    if (more) {
      const int ko = (kt + 1) * 128;
      #pragma unroll
      for (int c = 0; c < 8; ++c) areg[c] = *(const u32x4*)(Ab + offAg[c] + ko);
      const size_t kwo = (size_t)(kt + 1) * 64 * Nn;
      #pragma unroll
      for (int r = 0; r < RW; ++r) {
        if constexpr (BN == 128) wv4[r] = __builtin_nontemporal_load((const f32x4*)(W + offWg[r] + kwo));
        else                     wv2[r] = __builtin_nontemporal_load((const f32x2*)(W + offWg[r] + kwo));
      }
    }
    #pragma unroll
    for (int ks = 0; ks < 2; ++ks) {
      short8 bfr[NFW];
      #pragma unroll
      for (int nf = 0; nf < NFW; ++nf)
        bfr[nf] = *(const short8*)((const char*)Wt + bAddr[nf] + ks * BSTRIDE);
      short8 af[8];
      #pragma unroll
      for (int mf = 0; mf < 8; ++mf)
        af[mf] = *(const short8*)((const char*)Atile + (aAddr[mf] ^ (ks * 64)));
      #pragma unroll
      for (int mf = 0; mf < 8; ++mf)
        #pragma unroll
        for (int nf = 0; nf < NFW; ++nf)
          acc[mf][nf] = __builtin_amdgcn_mfma_f32_16x16x32_bf16(af[mf], bfr[nf], acc[mf][nf], 0, 0, 0);
    }
    __syncthreads();
    if (more) {
      #pragma unroll
      for (int c = 0; c < 8; ++c) *(u32x4*)((char*)Atile + offAl[c]) = areg[c];
      unsigned* w32 = (unsigned*)Wt;
      #pragma unroll
      for (int pr = 0; pr < RW / 2; ++pr)
        #pragma unroll
        for (int e = 0; e < CW; ++e) {
          float lo = (BN == 128) ? wv4[2 * pr][e] : wv2[2 * pr][e];
          float hi = (BN == 128) ? wv4[2 * pr + 1][e] : wv2[2 * pr + 1][e];
          w32[offWl[pr][e]] = packbf(lo, hi);
        }
    }
    __syncthreads();
  }

  float* Pk = P + ((size_t)kc * PV) * Nn + nbase;
  #pragma unroll
  for (int mf = 0; mf < 8; ++mf) {
    const int row0 = wm * 128 + mf * 16 + l4 * 4;
    #pragma unroll
    for (int ri = 0; ri < 4; ++ri) {
      const int row = row0 + ri;
      if (row < MV) {
        #pragma unroll
        for (int nf = 0; nf < NFW; ++nf) {
          const int col = (wn * NFW + nf) * 16 + lm;
          __builtin_nontemporal_store(acc[mf][nf][ri], Pk + (size_t)row * Nn + col);
        }
      }
    }
  }
}

// H = relu(sum_kc P1 + b1) -> bf16 into A2 T0 region
__global__ void k_ep1(const float* __restrict__ P1, const float* __restrict__ b1,
                      unsigned short* __restrict__ A2) {
  int gid = blockIdx.x * 256 + threadIdx.x;
  int row = gid / (NH / 4);
  int c = (gid % (NH / 4)) * 4;
  f32x4 s = {0.f, 0.f, 0.f, 0.f};
  #pragma unroll
  for (int kc = 0; kc < KC1; ++kc)
    s += __builtin_nontemporal_load((const f32x4*)(P1 + ((size_t)kc * PV + row) * NH + c));
  const f32x4 b = *(const f32x4*)(b1 + c);
  unsigned long long pack = 0;
  #pragma unroll
  for (int i = 0; i < 4; ++i) {
    float v = s[i] + b[i];
    pack |= (unsigned long long)f2bf(v > 0.f ? v : 0.f) << (16 * i);
  }
  *(unsigned long long*)(A2 + (size_t)row * K2 + c) = pack;
}

// ---------------- classifier input: zt[g][r][j] = sum_kc P2 + b2[r] (transposed) ----------------
// grid: 2 graphs * 25 j-tiles of 8; block 256
__global__ __launch_bounds__(256)
void k_zsum(const float* __restrict__ P2, const float* __restrict__ b2,
            float* __restrict__ zt) {
  __shared__ float tile[8][520];
  const int g = blockIdx.x / 25;
  const int j0 = (blockIdx.x % 25) * 8;
  const int t = threadIdx.x;
  const int j = t >> 5;              // 0..7
  const int c0 = (t & 31) * 16;      // 0..496
  const int row = g * NNODES + j0 + j;

  #pragma unroll
  for (int ci = 0; ci < 4; ++ci) {
    const int c = c0 + ci * 4;
    f32x4 s = *(const f32x4*)(b2 + c);
    #pragma unroll
    for (int kc = 0; kc < KC2; ++kc)
      s += __builtin_nontemporal_load((const f32x4*)(P2 + ((size_t)kc * PV + row) * NCL + c));
    *(f32x4*)&tile[j][c] = s;
  }
  __syncthreads();

  #pragma unroll
  for (int ci = 0; ci < 2; ++ci) {
    const int c = ci * 256 + t;
    f32x4 lo, hi;
    #pragma unroll
    for (int e = 0; e < 4; ++e) { lo[e] = tile[e][c]; hi[e] = tile[4 + e][c]; }
    float* zr = zt + ((size_t)g * NCL + c) * 200 + j0;
    *(f32x4*)zr = lo;
    *(f32x4*)(zr + 4) = hi;
  }
}

// ---------------- fused 3-layer classifier, one wave per output row ----------------
// grid: 2 * 128 blocks; block 256 (4 waves, 1 row each)
__global__ __launch_bounds__(256)
void k_cls2(const float* __restrict__ zt,
            const float* __restrict__ Wc1, const float* __restrict__ bc1,
            const float* __restrict__ Wc2, const float* __restrict__ bc2,
            const float* __restrict__ Wc3, const float* __restrict__ bc3,
            float* __restrict__ outp) {
  __shared__ float zs[4][200];
  __shared__ float h1s[4][100];
  __shared__ float h2s[4][50];
  const int g = blockIdx.x >> 7;
  const int t = threadIdx.x;
  const int w = t >> 6, lane = t & 63;
  const int r = (blockIdx.x & 127) * 4 + w;

  // stage z-row (contiguous 800 B)
  const float* zr = zt + ((size_t)g * NCL + r) * 200;
  #pragma unroll
  for (int i = 0; i < 4; ++i) {
    const int idx = i * 64 + lane;
    if (idx < 200) zs[w][idx] = zr[idx];
  }
  __syncthreads();

  // layer 1: 100 outputs; lane handles c0=lane and c1=lane+64 (clamped)
  {
    const int c0 = lane;
    const int c1 = lane + 64;
    const int c1m = (c1 < 100) ? c1 : 99;
    float a0 = bc1[c0 < 100 ? c0 : 99];
    float a1 = bc1[c1m];
    const float* w0 = Wc1 + c0 * 200;
    const float* w1 = Wc1 + c1m * 200;
    #pragma unroll 8
    for (int j = 0; j < 200; ++j) {
      const float zv = zs[w][j];
      a0 = fmaf(zv, w0[j], a0);
      a1 = fmaf(zv, w1[j], a1);
    }
    if (c0 < 100) h1s[w][c0] = a0 > 0.f ? a0 : 0.f;
    if (c1 < 100) h1s[w][c1] = a1 > 0.f ? a1 : 0.f;
  }
  __syncthreads();

  // layer 2: 50 outputs
  {
    const int c2 = (lane < 50) ? lane : 49;
    float b = bc2[c2];
    const float* w2 = Wc2 + c2 * 100;
    #pragma unroll 10
    for (int c = 0; c < 100; ++c) b = fmaf(h1s[w][c], w2[c], b);
    if (lane < 50) h2s[w][lane] = b > 0.f ? b : 0.f;
  }
  __syncthreads();

  // layer 3: dot-50 wave reduce
  {
    float v = (lane < 50) ? h2s[w][lane] * Wc3[lane] : 0.f;
    #pragma unroll
    for (int off = 32; off >= 1; off >>= 1) v += __shfl_down(v, off);
    if (lane == 0) outp[g * NCL + r] = v + bc3[0];
  }
}

extern "C" void kernel_launch(void* const* d_in, const int* in_sizes, int n_in,
                              void* d_out, int out_size, void* d_ws, size_t ws_size,
                              hipStream_t stream) {
  const float* x1  = (const float*)d_in[0];
  const int*   ei1 = (const int*)d_in[1];
  const float* ea1 = (const float*)d_in[2];
  const float* x2  = (const float*)d_in[3];
  const int*   ei2 = (const int*)d_in[4];
  const float* ea2 = (const float*)d_in[5];
  const float* W1  = (const float*)d_in[6];
  const float* b1  = (const float*)d_in[7];
  const float* W2  = (const float*)d_in[8];
  const float* b2  = (const float*)d_in[9];
  const float* Wc1 = (const float*)d_in[10];
  const float* bc1 = (const float*)d_in[11];
  const float* Wc2 = (const float*)d_in[12];
  const float* bc2 = (const float*)d_in[13];
  const float* Wc3 = (const float*)d_in[14];
  const float* bc3 = (const float*)d_in[15];
  float* outp = (float*)d_out;

  char* ws = (char*)d_ws;
  float*          P1  = (float*)(ws + OFF_P1);
  float*          P2  = (float*)(ws + OFF_P2);
  unsigned short* A1  = (unsigned short*)(ws + OFF_A1);
  unsigned short* A2  = (unsigned short*)(ws + OFF_A2);
  float*          deg = (float*)(ws + OFF_DEG);
  float*          Ld  = (float*)(ws + OFF_LD);
  unsigned short* LLb = (unsigned short*)(ws + OFF_LL);
  float*          zt  = (float*)(ws + OFF_Z);   // reuses P1 region (dead after k_ep1)

  k_zero<<<1871, 256, 0, stream>>>(
      (f32x4*)(ws + OFF_DEG), 48800,
      (f32x4*)(ws + OFF_A1 + (size_t)MV * K1 * 2), 344064,
      (f32x4*)(ws + OFF_A2 + (size_t)MV * K2 * 2), 86016);

  k_deg<<<63, 256, 0, stream>>>(ei1, ea1, ei2, ea2, deg);
  k_buildL<<<63, 256, 0, stream>>>(ei1, ea1, ei2, ea2, deg, Ld);
  k_LL<<<400, 256, 0, stream>>>(Ld, LLb);
  k_t0<<<1600, 256, 0, stream>>>(x1, x2, A1);
  k_abuild<<<(NF1 / 64) * 2, 256, 0, stream>>>(LLb, A1, A1, NF1, K1);
  k_gemm<128><<<KC1 * (NH / 128), 512, 0, stream>>>(W1, A1, P1, NH, BK1, K1);
  k_ep1<<<800, 256, 0, stream>>>(P1, b1, A2);
  k_abuild<<<(NH / 64) * 2, 256, 0, stream>>>(LLb, A2, A2, NH, K2);
  k_gemm<32><<<KC2 * (NCL / 32), 512, 0, stream>>>(W2, A2, P2, NCL, BK2, K2);
  k_zsum<<<50, 256, 0, stream>>>(P2, b2, zt);
  k_cls2<<<256, 256, 0, stream>>>(zt, Wc1, bc1, Wc2, bc2, Wc3, bc3, outp);
}